// Round 5
// baseline (138.213 us; speedup 1.0000x reference)
//
#include <hip/hip_runtime.h>
#include <hip/hip_bf16.h>
#include <stdint.h>

// VQ-VAE vector quantizer forward, MI355X (gfx950).
// z: [32,256,32,32] fp32 (NCHW), E: [1024,256] fp32.
// score(n,k) = 0.5*||e_k||^2 - <f_n,e_k>  (argmin-equivalent to d2)
// dots via bf16 MFMA 16x16x32 fp32-accum; gather exact fp32.
//
// R10: R6-R9 bracketing shows the main loop is NOT LDS-BW / occupancy /
// HBM bound -- the invariant across all ~46-55us variants is the 16-chunk
// staged-LDS skeleton (vmcnt-drain + full-block barrier x16). Esw is 512KB
// and L2-resident, so B needs no LDS: load B-frags straight from global
// into registers. 512 blocks x 256 thr (4 waves), 64 rows/block; each wave
// holds A-frags for ALL 64 rows (a[4][8], 128 VGPR) and owns 256 codes.
// Per 16-code tile: 8 coalesced dwordx4 loads (1KB/wave-instr, L2) feed 32
// MFMAs (4 MFMA per load vs 1 before), one-tile-ahead register double
// buffer, ZERO barriers in the main loop. dc-chain accumulation order
// unchanged -> bit-identical scores/argmin.

typedef short v8s __attribute__((ext_vector_type(8)));
typedef float v4f __attribute__((ext_vector_type(4)));

__device__ inline unsigned short f2bf(float f) {  // RNE fp32->bf16
    uint32_t u = __float_as_uint(f);
    return (unsigned short)((u + 0x7fffu + ((u >> 16) & 1u)) >> 16);
}

// ---- Kernel 1: E -> SWIZZLED Ebf bf16 + nE + accum/done=0 ------------------
// Unit for (k, dc, g): U = (k>>4)*512 + dc*64 + g*16 + (k&15),
// holding elems d = dc*32 + g*8 .. +8. Coalesced 16B stores.
__global__ __launch_bounds__(256) void k_prep_e(const float* __restrict__ E,
                                                v8s* __restrict__ Esw,
                                                float* __restrict__ nE,
                                                float* __restrict__ accum,
                                                unsigned* __restrict__ done) {
    __shared__ float Ef[16][264];
    int q = blockIdx.x, tid = threadIdx.x;
    const float4* Ein = (const float4*)(E + ((size_t)q << 12));
#pragma unroll
    for (int i = 0; i < 4; i++) {
        int f4 = i * 256 + tid;
        int row = f4 >> 6, c4 = (f4 & 63) << 2;
        *(float4*)&Ef[row][c4] = Ein[f4];
    }
    __syncthreads();
    {
        int c = tid >> 4, l = tid & 15;
        float s = 0.f;
#pragma unroll
        for (int j = 0; j < 16; j++) { float v = Ef[c][l + 16 * j]; s += v * v; }
#pragma unroll
        for (int off = 1; off < 16; off <<= 1) s += __shfl_xor(s, off);
        if (l == 0) nE[q * 16 + c] = 0.5f * s;
    }
#pragma unroll
    for (int i = 0; i < 2; i++) {
        int u = tid + i * 256;
        int um = u & 15, ug = (u >> 4) & 3, udc = (u >> 6) & 7;
        int d0 = udc * 32 + ug * 8;
        union { v8s v; unsigned short s[8]; } pk;
#pragma unroll
        for (int e = 0; e < 8; e++) pk.s[e] = f2bf(Ef[um][d0 + e]);
        Esw[((size_t)q << 9) + u] = pk.v;
    }
    if (q == 0 && tid == 0) { accum[0] = 0.f; done[0] = 0u; }
}

// ---- Kernel 2: fused transpose+GEMM+argmin+gather+output+loss ---------------
__global__ __launch_bounds__(256, 2) void k_main(
        const v8s* __restrict__ Esw,
        const float* __restrict__ nE,
        const float* __restrict__ z,
        const float* __restrict__ E,
        float* __restrict__ out,
        float* __restrict__ accum,
        unsigned* __restrict__ done) {
    __shared__ union {
        unsigned char A[32768];     // swizzled bf16 A-tile: 64 rows x 512 B
        float4 Eg4[2048];           // epilogue swizzled tile (32 KB)
    } S;
    __shared__ float nEl[1024];
    __shared__ unsigned long long pairLds[64][4];
    __shared__ float nrmLds[64];
    __shared__ int   idxLds[64];

    int tid = threadIdx.x;
    int lane = tid & 63, w = tid >> 6;         // 4 waves = 4 code-groups
    int g = lane >> 4, m = lane & 15;          // MFMA lane coords
    int R0 = blockIdx.x << 6;                  // 64 rows/block
    int b = R0 >> 10, hw0 = R0 & 1023;

    // ---- A-prep: z[b][0..256][hw0..hw0+64] -> swizzled bf16 LDS tile -------
    // Thread (q=tid&15, dblk=tid>>4) loads 16 d-rows x float4 at hw quad 4q
    // in 2 passes, repacks to 8 v8s. Swizzle sl^((r^r>>2)&7) keeps writes and
    // fragment reads at the ds b128 bank floor.
    {
        int q = tid & 15, dblk = tid >> 4;     // hw = hw0+4q, d rows dblk*16..
        const float* zp = z + ((size_t)b << 18) + hw0 + (q << 2);
#pragma unroll
        for (int s = 0; s < 2; s++) {
            float4 L[8];
#pragma unroll
            for (int j = 0; j < 8; j++)
                L[j] = *(const float4*)(zp + (size_t)(((dblk << 4) + (s << 3) + j) << 10));
            const float* Lf = (const float*)L;
            int sl = (dblk << 1) + s;          // v8s slot 0..31
#pragma unroll
            for (int c = 0; c < 4; c++) {
                union { v8s v; unsigned short u[8]; } pk;
#pragma unroll
                for (int j = 0; j < 8; j++) pk.u[j] = f2bf(Lf[j * 4 + c]);
                int r = (q << 2) + c;
                int sw = sl ^ ((r ^ (r >> 2)) & 7);
                *(v8s*)(&S.A[(r << 9) + (sw << 4)]) = pk.v;
            }
        }
    }
#pragma unroll
    for (int i = 0; i < 4; i++) nEl[tid + (i << 8)] = nE[tid + (i << 8)];
    __syncthreads();                           // A-tile resident

    // A frags: ALL 64 rows per wave (4 M-tiles); row norms -> nrmLds (wave 0).
    v8s a[4][8];
#pragma unroll
    for (int mt = 0; mt < 4; mt++) {
        int r = (mt << 4) + m;
        int f = (r ^ (r >> 2)) & 7;
#pragma unroll
        for (int dc = 0; dc < 8; dc++) {
            int sw = ((dc << 2) + g) ^ f;
            a[mt][dc] = *(const v8s*)(&S.A[(r << 9) + (sw << 4)]);
        }
    }
    if (w == 0) {
#pragma unroll
        for (int mt = 0; mt < 4; mt++) {
            float nrm = 0.f;
#pragma unroll
            for (int dc = 0; dc < 8; dc++) {
                union { v8s v; unsigned short u[8]; } un; un.v = a[mt][dc];
#pragma unroll
                for (int j = 0; j < 8; j++) {
                    float v = __uint_as_float((uint32_t)un.u[j] << 16);
                    nrm = fmaf(v, v, nrm);
                }
            }
            nrm += __shfl_xor(nrm, 16);        // reduce over g: full ||z_row||^2
            nrm += __shfl_xor(nrm, 32);
            if (g == 0) nrmLds[(mt << 4) + m] = nrm;
        }
    }

    // ---- main loop: B direct global->reg, no LDS, no barriers --------------
    // Wave w owns codes [w*256, w*256+256): 16 tiles of 16 codes. Per tile:
    // 8 contiguous 1KB wave-loads (L2-hit) double-buffered one tile ahead.
    float best[4][4]; int bidx[4][4];
#pragma unroll
    for (int mt = 0; mt < 4; mt++)
#pragma unroll
        for (int r = 0; r < 4; r++) { best[mt][r] = 3.4e38f; bidx[mt][r] = 0; }

    const v8s* Bq = Esw + ((size_t)(w << 4) << 9) + (g << 4) + m;
    v8s bb[2][8];
#pragma unroll
    for (int dc = 0; dc < 8; dc++) bb[0][dc] = Bq[dc << 6];
    int c0 = (w << 8) + m;                     // this lane's code within tile 0
#pragma unroll 2
    for (int ct = 0; ct < 16; ct++) {
        int cur = ct & 1;                      // static after unroll 2
        const v8s* Bn = Bq + 512;
        if (ct < 15) {
#pragma unroll
            for (int dc = 0; dc < 8; dc++) bb[cur ^ 1][dc] = Bn[dc << 6];
        }
        v4f acc[4];
#pragma unroll
        for (int mt = 0; mt < 4; mt++) acc[mt] = (v4f){0.f, 0.f, 0.f, 0.f};
#pragma unroll
        for (int dc = 0; dc < 8; dc++) {       // 4 indep chains, dep dist 4
#pragma unroll
            for (int mt = 0; mt < 4; mt++)
                acc[mt] = __builtin_amdgcn_mfma_f32_16x16x32_bf16(
                              a[mt][dc], bb[cur][dc], acc[mt], 0, 0, 0);
        }
        float ne = nEl[c0 + (ct << 4)];
        int code = c0 + (ct << 4);
#pragma unroll
        for (int mt = 0; mt < 4; mt++)         // ascending ct: tie -> low idx
#pragma unroll
            for (int r = 0; r < 4; r++) {
                float s0 = ne - acc[mt][r];
                if (s0 < best[mt][r]) { best[mt][r] = s0; bidx[mt][r] = code; }
            }
        Bq = Bn;
    }

    // per-wave winner reduce over 16 code-columns (pack: min => low score,
    // low idx); 4 code-groups meet in pairLds.
#pragma unroll
    for (int mt = 0; mt < 4; mt++)
#pragma unroll
        for (int r = 0; r < 4; r++) {
            uint32_t sb = __float_as_uint(best[mt][r]);
            sb = (sb & 0x80000000u) ? ~sb : (sb | 0x80000000u);
            unsigned long long pk = ((unsigned long long)sb << 32) | (uint32_t)bidx[mt][r];
#pragma unroll
            for (int off = 1; off < 16; off <<= 1) {
                unsigned long long o = __shfl_xor(pk, off);
                if (o < pk) pk = o;
            }
            if (m == 0)                        // C/D row = g*4 + r
                pairLds[(mt << 4) + (g << 2) + r][w] = pk;
        }
    __syncthreads();                           // winners visible; A-tile free

    // combine code-groups + loss (wave 0): ||e*-z||^2 = 2*s* + ||z||^2.
    if (tid < 64) {
        unsigned long long pk = pairLds[tid][0];
#pragma unroll
        for (int c = 1; c < 4; c++) {
            unsigned long long o = pairLds[tid][c];
            if (o < pk) pk = o;
        }
        idxLds[tid] = (int)(pk & 0xffffffffu);
        uint32_t t = (uint32_t)(pk >> 32);
        float sc = __uint_as_float((t & 0x80000000u) ? (t & 0x7fffffffu) : ~t);
        float ls = 2.0f * sc + nrmLds[tid];
#pragma unroll
        for (int off = 1; off < 64; off <<= 1) ls += __shfl_xor(ls, off);
        if (tid == 0) atomicAdd(accum, ls);
    }
    __syncthreads();                           // idxLds visible for epilogue

    // epilogue: gather E rows + coalesced NCHW writes via XOR-swizzled tile.
    float* ob = out + ((size_t)b << 18);
    int hwl = tid & 31, dq0 = tid >> 5;        // dq0: 0..7
#pragma unroll 1
    for (int ph = 0; ph < 2; ph++) {
#pragma unroll
        for (int i = 0; i < 8; i++) {          // rows w*8+i (wave-uniform)
            int row = (w << 3) + i;
            int k = idxLds[(ph << 5) + row];
            float4 v = ((const float4*)(E + ((size_t)k << 8)))[lane];
            S.Eg4[(row << 6) + (lane ^ row)] = v;
        }
        __syncthreads();
        int hwp = hw0 + (ph << 5) + hwl;
#pragma unroll
        for (int i = 0; i < 8; i++) {
            int dq = (i << 3) + dq0;
            float4 ev = S.Eg4[(hwl << 6) + (dq ^ hwl)];
            size_t o = ((size_t)dq << 12) + hwp;        // (4*dq)*1024 + hwp
            ob[o] = ev.x; ob[o + 1024] = ev.y; ob[o + 2048] = ev.z; ob[o + 3072] = ev.w;
        }
        __syncthreads();                        // tile reused next phase
    }

    // fused scalar epilogue (last block writes outputs).
    if (tid == 0) {
        __threadfence();
        unsigned old = atomicAdd(done, 1u);
        if (old == 511u) {
            float s = atomicAdd(accum, 0.f) * (1.0f / 8388608.0f);
            out[8388608] = 1.25f * s;
            out[8388609] = s;
            out[8388610] = s;
        }
    }
}

extern "C" void kernel_launch(void* const* d_in, const int* in_sizes, int n_in,
                              void* d_out, int out_size, void* d_ws, size_t ws_size,
                              hipStream_t stream) {
    const float* z = (const float*)d_in[0];
    const float* E = (const float*)d_in[1];
    char* ws = (char*)d_ws;
    v8s*      Esw   = (v8s*)(ws);                // 524,288 B
    float*    nE    = (float*)(ws + 524288);     //   4,096 B
    float*    accum = (float*)(ws + 528384);     //       4 B
    unsigned* done  = (unsigned*)(ws + 528388);  //       4 B
    float* out = (float*)d_out;

    hipLaunchKernelGGL(k_prep_e, dim3(64),  dim3(256), 0, stream, E, Esw, nE, accum, done);
    hipLaunchKernelGGL(k_main,   dim3(512), dim3(256), 0, stream,
                       Esw, nE, z, E, out, accum, done);
}

// Round 6
// 116.942 us; speedup vs baseline: 1.1819x; 1.1819x over previous
//
#include <hip/hip_runtime.h>
#include <hip/hip_bf16.h>
#include <stdint.h>

// VQ-VAE vector quantizer forward, MI355X (gfx950).
// z: [32,256,32,32] fp32 (NCHW), E: [1024,256] fp32.
// score(n,k) = 0.5*||e_k||^2 - <f_n,e_k>  (argmin-equivalent to d2)
// dots via bf16 MFMA 16x16x32 fp32-accum; gather exact fp32.
//
// R11: R6 structure restored verbatim (proven best: 46us; R7-R10
// restructures all regressed). Cost model: per-CU serial A-prep 5.4 +
// mainloop ~20.5 (ds_read_b128 floor) + epilogue 5.5 + ~11us of
// barrier-event residual (16x vmcnt(0)-drain + 8-wave converge + VALU
// tail). Single change: BK=128-code chunks (2x64KB dbuf, 8 iterations)
// -- same LDS bytes, same MFMA count, same 8-dc chain order (scores
// bit-identical), but HALF the drain/barrier events and 2x longer
// uninterrupted compute runs. 1 block/CU already, so the 134KB LDS
// costs no occupancy.

typedef short v8s __attribute__((ext_vector_type(8)));
typedef float v4f __attribute__((ext_vector_type(4)));

__device__ inline unsigned short f2bf(float f) {  // RNE fp32->bf16
    uint32_t u = __float_as_uint(f);
    return (unsigned short)((u + 0x7fffu + ((u >> 16) & 1u)) >> 16);
}

// ---- Kernel 1: E -> SWIZZLED Ebf bf16 + nE + accum/done=0 ------------------
// Unit for (k, dc, g): U = (k>>4)*512 + dc*64 + g*16 + (k&15),
// holding elems d = dc*32 + g*8 .. +8. Coalesced 16B stores.
__global__ __launch_bounds__(256) void k_prep_e(const float* __restrict__ E,
                                                v8s* __restrict__ Esw,
                                                float* __restrict__ nE,
                                                float* __restrict__ accum,
                                                unsigned* __restrict__ done) {
    __shared__ float Ef[16][264];
    int q = blockIdx.x, tid = threadIdx.x;
    const float4* Ein = (const float4*)(E + ((size_t)q << 12));
#pragma unroll
    for (int i = 0; i < 4; i++) {
        int f4 = i * 256 + tid;
        int row = f4 >> 6, c4 = (f4 & 63) << 2;
        *(float4*)&Ef[row][c4] = Ein[f4];
    }
    __syncthreads();
    {
        int c = tid >> 4, l = tid & 15;
        float s = 0.f;
#pragma unroll
        for (int j = 0; j < 16; j++) { float v = Ef[c][l + 16 * j]; s += v * v; }
#pragma unroll
        for (int off = 1; off < 16; off <<= 1) s += __shfl_xor(s, off);
        if (l == 0) nE[q * 16 + c] = 0.5f * s;
    }
#pragma unroll
    for (int i = 0; i < 2; i++) {
        int u = tid + i * 256;
        int um = u & 15, ug = (u >> 4) & 3, udc = (u >> 6) & 7;
        int d0 = udc * 32 + ug * 8;
        union { v8s v; unsigned short s[8]; } pk;
#pragma unroll
        for (int e = 0; e < 8; e++) pk.s[e] = f2bf(Ef[um][d0 + e]);
        Esw[((size_t)q << 9) + u] = pk.v;
    }
    if (q == 0 && tid == 0) { accum[0] = 0.f; done[0] = 0u; }
}

// ---- Kernel 2: fused transpose+GEMM+argmin+gather+output+loss ---------------
__global__ __launch_bounds__(512) void k_main(
        const v8s* __restrict__ Esw,
        const float* __restrict__ nE,
        const float* __restrict__ z,
        const float* __restrict__ E,
        float* __restrict__ out,
        float* __restrict__ accum,
        unsigned* __restrict__ done) {
    __shared__ union {
        v8s    B[2][4096];          // 2 x 64 KB double-buffer (A-tile 64KB fits)
        float4 Eg4[2048];           // epilogue swizzled tile (32 KB)
    } S;
    __shared__ float nEl[1024];
    __shared__ float nrmLds[128];
    __shared__ int   idxLds[128];
    __shared__ float w8[8];

    int tid = threadIdx.x;
    int lane = tid & 63, w = tid >> 6;         // 8 waves
    int g = lane >> 4, m = lane & 15;          // MFMA lane coords
    int R0 = blockIdx.x << 7;                  // 128 rows/block
    int b = R0 >> 10, hw0 = R0 & 1023;

    // ---- A-prep: z[b][0..256][hw0..hw0+128] -> swizzled bf16 LDS tile ------
    // Thread (q=tid&31, dblk=tid>>5) loads 16 d-rows x float4 at hw quad 4q,
    // repacks to 8 v8s (4 rows x 2 slots). Swizzle slot^((row^row>>2)&7)
    // spreads both the row%4-strided writes and the row-varying frag reads
    // across all 8 bank-quads (b128 floor, no serialization beyond it).
    {
        int q = tid & 31, dblk = tid >> 5;     // hw = hw0+4q, d base = dblk*16
        const float* zp = z + ((size_t)b << 18) + hw0 + (q << 2);
#pragma unroll
        for (int s = 0; s < 2; s++) {
            float4 L[8];
#pragma unroll
            for (int j = 0; j < 8; j++)
                L[j] = *(const float4*)(zp + (size_t)(((dblk << 4) + (s << 3) + j) << 10));
            const float* Lf = (const float*)L;
            int slot = (dblk << 1) + s;
#pragma unroll
            for (int c = 0; c < 4; c++) {
                union { v8s v; unsigned short u[8]; } pk;
#pragma unroll
                for (int j = 0; j < 8; j++) pk.u[j] = f2bf(Lf[j * 4 + c]);
                int row = (q << 2) + c;
                int sw = slot ^ ((row ^ (row >> 2)) & 7);
                *(v8s*)((char*)&S + (row << 9) + (sw << 4)) = pk.v;
            }
        }
    }
#pragma unroll
    for (int i = 0; i < 2; i++) nEl[tid + i * 512] = nE[tid + i * 512];
    __syncthreads();                           // A-tile resident

    // A frags: 16 rows/wave, from LDS; row norm from the same bf16 values
    // (matches the dot's rounding; loss error ~1e-6 after the 8.4M mean).
    v8s a[8];
    {
        int row = (w << 4) + m;
        int f = (row ^ (row >> 2)) & 7;
#pragma unroll
        for (int dc = 0; dc < 8; dc++) {
            int sw = ((dc << 2) + g) ^ f;
            a[dc] = *(const v8s*)((const char*)&S + (row << 9) + (sw << 4));
        }
        float nrm = 0.f;
#pragma unroll
        for (int dc = 0; dc < 8; dc++) {
            union { v8s v; unsigned short u[8]; } un; un.v = a[dc];
#pragma unroll
            for (int j = 0; j < 8; j++) {
                float v = __uint_as_float((uint32_t)un.u[j] << 16);
                nrm = fmaf(v, v, nrm);
            }
        }
        nrm += __shfl_xor(nrm, 16);            // reduce over g: full ||z_row||^2
        nrm += __shfl_xor(nrm, 32);
        if (g == 0) nrmLds[row] = nrm;
    }
    __syncthreads();                           // A-tile consumed; S free for B

    // contiguous staging: chunk = 4096 v8s (64 KB); thread stages j*512+tid
#define STAGE(ch, buf)                                                        \
    {                                                                         \
        _Pragma("unroll")                                                     \
        for (int j = 0; j < 8; j++) {                                         \
            __builtin_amdgcn_global_load_lds(                                 \
                (const __attribute__((address_space(1))) void*)               \
                    (Esw + ((size_t)(ch) << 12) + (j << 9) + (w << 6) + lane),\
                (__attribute__((address_space(3))) void*)                     \
                    &S.B[buf][(j << 9) + (w << 6)],                           \
                16, 0, 0);                                                    \
        }                                                                     \
    }

    float best[4]; int bidx[4];
#pragma unroll
    for (int r = 0; r < 4; r++) { best[r] = 3.4e38f; bidx[r] = 0; }

    STAGE(0, 0);
#pragma unroll 2
    for (int ct = 0; ct < 8; ct++) {
        int cur = ct & 1;                      // static after unroll 2
        __syncthreads();                       // chunk ct resident
        if (ct < 7) STAGE(ct + 1, cur ^ 1);
        float ne[8];
#pragma unroll
        for (int t = 0; t < 8; t++) ne[t] = nEl[(ct << 7) + (t << 4) + m];
        v4f acc[8];
#pragma unroll
        for (int t = 0; t < 8; t++) acc[t] = (v4f){0.f, 0.f, 0.f, 0.f};
#pragma unroll
        for (int dc = 0; dc < 8; dc++) {       // 8 indep chains/wave
#pragma unroll
            for (int t = 0; t < 8; t++) {
                v8s bf = S.B[cur][t * 512 + dc * 64 + g * 16 + m];
                acc[t] = __builtin_amdgcn_mfma_f32_16x16x32_bf16(a[dc], bf, acc[t], 0, 0, 0);
            }
        }
#pragma unroll
        for (int t = 0; t < 8; t++) {          // ascending code: tie -> low idx
            int code = (ct << 7) + (t << 4) + m;
#pragma unroll
            for (int r = 0; r < 4; r++) {
                float s0 = ne[t] - acc[t][r];
                if (s0 < best[r]) { best[r] = s0; bidx[r] = code; }
            }
        }
    }

    // winner reduce over 16 code-columns (pack: min => low score, low idx);
    // loss per row folded in: ||e* - z||^2 = 2*s* + ||z||^2.
    float lsum = 0.f;
#pragma unroll
    for (int r = 0; r < 4; r++) {
        uint32_t sb = __float_as_uint(best[r]);
        sb = (sb & 0x80000000u) ? ~sb : (sb | 0x80000000u);
        unsigned long long pk = ((unsigned long long)sb << 32) | (uint32_t)bidx[r];
#pragma unroll
        for (int off = 1; off < 16; off <<= 1) {
            unsigned long long o = __shfl_xor(pk, off);
            if (o < pk) pk = o;
        }
        int row = (w << 4) + (g << 2) + r;
        if (m == 0) {                          // C/D row = g*4 + r
            idxLds[row] = (int)(pk & 0xffffffffu);
            uint32_t t = (uint32_t)(pk >> 32);
            float sw = __uint_as_float((t & 0x80000000u) ? (t & 0x7fffffffu) : ~t);
            lsum += 2.0f * sw + nrmLds[row];
        }
    }
#pragma unroll
    for (int off = 1; off < 64; off <<= 1) lsum += __shfl_xor(lsum, off);
    if (lane == 0) w8[w] = lsum;
    __syncthreads();                           // winners visible; B free

    // epilogue: gather E rows + coalesced NCHW writes via XOR-swizzled tile.
    float* ob = out + ((size_t)b << 18);
    int hwl = tid & 31, dq0 = tid >> 5;        // dq0: 0..15
#pragma unroll 1
    for (int ph = 0; ph < 4; ph++) {
#pragma unroll
        for (int i = 0; i < 4; i++) {          // rows w + 8i (wave-uniform)
            int row = w + (i << 3);
            int k = idxLds[(ph << 5) + row];
            float4 v = ((const float4*)(E + ((size_t)k << 8)))[lane];
            S.Eg4[(row << 6) + (lane ^ row)] = v;
        }
        __syncthreads();
        int hwp = hw0 + (ph << 5) + hwl;
#pragma unroll
        for (int i = 0; i < 4; i++) {
            int dq = dq0 + (i << 4);
            float4 ev = S.Eg4[(hwl << 6) + (dq ^ hwl)];
            size_t o = ((size_t)dq << 12) + hwp;        // (4*dq)*1024 + hwp
            ob[o] = ev.x; ob[o + 1024] = ev.y; ob[o + 2048] = ev.z; ob[o + 3072] = ev.w;
        }
        __syncthreads();                        // tile reused next phase
    }

    // loss accumulate + fused scalar epilogue (last block writes outputs).
    if (tid == 0) {
        float s8 = 0.f;
#pragma unroll
        for (int i = 0; i < 8; i++) s8 += w8[i];
        atomicAdd(accum, s8);
        __threadfence();
        unsigned old = atomicAdd(done, 1u);
        if (old == 255u) {
            float s = atomicAdd(accum, 0.f) * (1.0f / 8388608.0f);
            out[8388608] = 1.25f * s;
            out[8388609] = s;
            out[8388610] = s;
        }
    }
#undef STAGE
}

extern "C" void kernel_launch(void* const* d_in, const int* in_sizes, int n_in,
                              void* d_out, int out_size, void* d_ws, size_t ws_size,
                              hipStream_t stream) {
    const float* z = (const float*)d_in[0];
    const float* E = (const float*)d_in[1];
    char* ws = (char*)d_ws;
    v8s*      Esw   = (v8s*)(ws);                // 524,288 B
    float*    nE    = (float*)(ws + 524288);     //   4,096 B
    float*    accum = (float*)(ws + 528384);     //       4 B
    unsigned* done  = (unsigned*)(ws + 528388);  //       4 B
    float* out = (float*)d_out;

    hipLaunchKernelGGL(k_prep_e, dim3(64),  dim3(256), 0, stream, E, Esw, nE, accum, done);
    hipLaunchKernelGGL(k_main,   dim3(256), dim3(512), 0, stream,
                       Esw, nE, z, E, out, accum, done);
}